// Round 2
// baseline (26.334 us; speedup 1.0000x reference)
//
#include <hip/hip_runtime.h>
#include <math.h>

#define EPS 1e-6f

constexpr int BLK = 256;     // threads per block
constexpr int NCHUNK = 8;    // l-chunks (grid.y)
constexpr int MAX_CL = 1024; // LDS float4 capacity (16 KiB)

// Per (b, m, l-chunk): partial min over the chunk of ||p_l - q_m||^2 where
// q = c2 - eps, using the dot expansion min_l(||p||^2 - 2 p.q) + ||q||^2.
// Merge across chunks via atomicMin on the uint bits (valid: values >= 0).
__global__ void __launch_bounds__(BLK)
k_min(const float* __restrict__ c1, const float* __restrict__ c2,
      unsigned int* __restrict__ wsmin, int L1, int L2, int CL) {
    __shared__ float4 tile[MAX_CL];

    const int b = blockIdx.z;
    const int chunk = blockIdx.y;
    const int l0 = chunk * CL;
    const int nl = min(CL, L1 - l0);

    // Stage chunk of contour1, packed as (||p||^2, -2x, -2y, -2z).
    const float* src = c1 + ((size_t)b * L1 + l0) * 3;
    for (int i = threadIdx.x; i < nl; i += BLK) {
        float x = src[3 * i], y = src[3 * i + 1], z = src[3 * i + 2];
        tile[i] = make_float4(fmaf(x, x, fmaf(y, y, z * z)),
                              -2.0f * x, -2.0f * y, -2.0f * z);
    }
    __syncthreads();

    const int m = blockIdx.x * BLK + threadIdx.x;
    if (m >= L2) return;

    const float* q = c2 + ((size_t)b * L2 + m) * 3;
    const float q0 = q[0] - EPS, q1 = q[1] - EPS, q2 = q[2] - EPS;

    // 4 independent min accumulators to break the fmin dependence chain.
    float mn0 = 3.402823466e+38f, mn1 = mn0, mn2 = mn0, mn3 = mn0;
    int l = 0;
    for (; l + 4 <= nl; l += 4) {
        float4 pa = tile[l], pb = tile[l + 1], pc = tile[l + 2], pd = tile[l + 3];
        float ta = fmaf(pa.w, q2, fmaf(pa.z, q1, fmaf(pa.y, q0, pa.x)));
        float tb = fmaf(pb.w, q2, fmaf(pb.z, q1, fmaf(pb.y, q0, pb.x)));
        float tc = fmaf(pc.w, q2, fmaf(pc.z, q1, fmaf(pc.y, q0, pc.x)));
        float td = fmaf(pd.w, q2, fmaf(pd.z, q1, fmaf(pd.y, q0, pd.x)));
        mn0 = fminf(mn0, ta);
        mn1 = fminf(mn1, tb);
        mn2 = fminf(mn2, tc);
        mn3 = fminf(mn3, td);
    }
    for (; l < nl; ++l) {
        float4 p = tile[l];
        mn0 = fminf(mn0, fmaf(p.w, q2, fmaf(p.z, q1, fmaf(p.y, q0, p.x))));
    }
    float mn = fminf(fminf(mn0, mn1), fminf(mn2, mn3));

    const float qq = fmaf(q0, q0, fmaf(q1, q1, q2 * q2));
    mn = fmaxf(mn + qq, 0.0f);

    atomicMin(&wsmin[(size_t)b * L2 + m], __float_as_uint(mn));
}

// Per b: out[b] = resolution * mean_m sqrt(min_dist2[b,m]).
__global__ void __launch_bounds__(BLK)
k_reduce(const unsigned int* __restrict__ wsmin, const float* __restrict__ res,
         float* __restrict__ out, int L2) {
    const int b = blockIdx.x;
    float sum = 0.0f;
    for (int m = threadIdx.x; m < L2; m += BLK)
        sum += sqrtf(__uint_as_float(wsmin[(size_t)b * L2 + m]));

    __shared__ float red[BLK];
    red[threadIdx.x] = sum;
    __syncthreads();
    for (int s = BLK / 2; s > 0; s >>= 1) {
        if (threadIdx.x < s) red[threadIdx.x] += red[threadIdx.x + s];
        __syncthreads();
    }
    if (threadIdx.x == 0) out[b] = red[0] * res[0] / (float)L2;
}

extern "C" void kernel_launch(void* const* d_in, const int* in_sizes, int n_in,
                              void* d_out, int out_size, void* d_ws, size_t ws_size,
                              hipStream_t stream) {
    const float* c1  = (const float*)d_in[0];
    const float* c2  = (const float*)d_in[1];
    const float* res = (const float*)d_in[2];
    float* out = (float*)d_out;

    const int B = out_size;                 // 4
    const int D = 3;
    const int L1 = in_sizes[0] / (B * D);   // 4096
    const int L2 = in_sizes[1] / (B * D);   // 4096

    unsigned int* wsmin = (unsigned int*)d_ws;  // B*L2 uints = 64 KiB

    // Init partial mins to 0xFFFFFFFF (greater than any finite f32 bit pattern).
    hipMemsetAsync(wsmin, 0xFF, (size_t)B * L2 * sizeof(unsigned int), stream);

    const int CL = (L1 + NCHUNK - 1) / NCHUNK;  // 512
    dim3 grid((L2 + BLK - 1) / BLK, NCHUNK, B);
    k_min<<<grid, BLK, 0, stream>>>(c1, c2, wsmin, L1, L2, CL);
    k_reduce<<<B, BLK, 0, stream>>>(wsmin, res, out, L2);
}

// Round 4
// 19.504 us; speedup vs baseline: 1.3502x; 1.3502x over previous
//
#include <hip/hip_runtime.h>
#include <math.h>

#define EPS 1e-6f
#define FLT_BIG 3.402823466e+38f

constexpr int BLK = 256;     // threads per block
constexpr int MPT = 4;       // m's per thread (register blocking)
constexpr int NCHUNK = 32;   // l-chunks (grid.y of k_min)
constexpr int MAXCL = 256;   // LDS float4 capacity (4 KiB)
constexpr int NSLICE = 8;    // m-slices in k_sqsum

// Per (b, chunk): stage CL points of contour1 as (||p||^2, -2x, -2y, -2z),
// then each thread computes, for 4 m's, the chunk-partial
//   min_l(||p||^2 - 2 p.q) + ||q||^2   with q = c2[m] - eps,
// and writes it to part[b][chunk][m]. No atomics, fixed order.
__global__ void __launch_bounds__(BLK)
k_min(const float* __restrict__ c1, const float* __restrict__ c2,
      float* __restrict__ part, int L1, int L2, int CL) {
    __shared__ float4 tile[MAXCL];

    const int b = blockIdx.z;
    const int chunk = blockIdx.y;
    const int l0 = chunk * CL;
    const int nl = min(CL, L1 - l0);

    const float* src = c1 + ((size_t)b * L1 + l0) * 3;
    for (int i = threadIdx.x; i < nl; i += BLK) {
        float x = src[3 * i], y = src[3 * i + 1], z = src[3 * i + 2];
        tile[i] = make_float4(fmaf(x, x, fmaf(y, y, z * z)),
                              -2.0f * x, -2.0f * y, -2.0f * z);
    }
    __syncthreads();

    const int mbase = blockIdx.x * (BLK * MPT) + threadIdx.x;

    float q0[MPT], q1[MPT], q2[MPT], mn[MPT];
    #pragma unroll
    for (int j = 0; j < MPT; ++j) {
        const int m = mbase + j * BLK;
        if (m < L2) {
            const float* q = c2 + ((size_t)b * L2 + m) * 3;
            q0[j] = q[0] - EPS; q1[j] = q[1] - EPS; q2[j] = q[2] - EPS;
        } else {
            q0[j] = q1[j] = q2[j] = 0.0f;
        }
        mn[j] = FLT_BIG;
    }

    #pragma unroll 4
    for (int l = 0; l < nl; ++l) {
        float4 p = tile[l];            // uniform-address broadcast ds_read_b128
        #pragma unroll
        for (int j = 0; j < MPT; ++j) {
            float t = fmaf(p.y, q0[j], p.x);
            t = fmaf(p.z, q1[j], t);
            t = fmaf(p.w, q2[j], t);
            mn[j] = fminf(mn[j], t);
        }
    }

    float* dst = part + ((size_t)b * NCHUNK + chunk) * L2;
    #pragma unroll
    for (int j = 0; j < MPT; ++j) {
        const int m = mbase + j * BLK;
        if (m < L2) {
            const float qq = fmaf(q0[j], q0[j], fmaf(q1[j], q1[j], q2[j] * q2[j]));
            dst[m] = mn[j] + qq;
        }
    }
}

// Per (b, m-slice): min across chunks, sqrt, partial sum over the slice.
__global__ void __launch_bounds__(BLK)
k_sqsum(const float* __restrict__ part, float* __restrict__ psum,
        int L2, int SL) {
    const int b = blockIdx.y;
    const int slice = blockIdx.x;
    const int m0 = slice * SL;
    const int mend = min(m0 + SL, L2);

    float sum = 0.0f;
    for (int m = m0 + threadIdx.x; m < mend; m += BLK) {
        float v = FLT_BIG;
        #pragma unroll 8
        for (int c = 0; c < NCHUNK; ++c)
            v = fminf(v, part[((size_t)b * NCHUNK + c) * L2 + m]);
        sum += sqrtf(fmaxf(v, 0.0f));
    }

    __shared__ float red[BLK];
    red[threadIdx.x] = sum;
    __syncthreads();
    for (int s = BLK / 2; s > 0; s >>= 1) {
        if (threadIdx.x < s) red[threadIdx.x] += red[threadIdx.x + s];
        __syncthreads();
    }
    if (threadIdx.x == 0) psum[b * NSLICE + slice] = red[0];
}

// out[b] = res * (sum of slice partials) / L2. Fixed order, deterministic.
__global__ void k_final(const float* __restrict__ psum, const float* __restrict__ res,
                        float* __restrict__ out, int B, int L2) {
    const int b = threadIdx.x;
    if (b < B) {
        float s = 0.0f;
        for (int j = 0; j < NSLICE; ++j) s += psum[b * NSLICE + j];
        out[b] = s * res[0] / (float)L2;
    }
}

extern "C" void kernel_launch(void* const* d_in, const int* in_sizes, int n_in,
                              void* d_out, int out_size, void* d_ws, size_t ws_size,
                              hipStream_t stream) {
    const float* c1  = (const float*)d_in[0];
    const float* c2  = (const float*)d_in[1];
    const float* res = (const float*)d_in[2];
    float* out = (float*)d_out;

    const int B = out_size;                 // 4
    const int D = 3;
    const int L1 = in_sizes[0] / (B * D);   // 4096
    const int L2 = in_sizes[1] / (B * D);   // 4096

    float* part = (float*)d_ws;                       // B*NCHUNK*L2 floats (2 MiB)
    float* psum = part + (size_t)B * NCHUNK * L2;     // B*NSLICE floats

    const int CL = (L1 + NCHUNK - 1) / NCHUNK;        // 128
    dim3 g1((L2 + BLK * MPT - 1) / (BLK * MPT), NCHUNK, B);
    k_min<<<g1, BLK, 0, stream>>>(c1, c2, part, L1, L2, CL);

    const int SL = (L2 + NSLICE - 1) / NSLICE;        // 512
    dim3 g2(NSLICE, B);
    k_sqsum<<<g2, BLK, 0, stream>>>(part, psum, L2, SL);

    k_final<<<1, 64, 0, stream>>>(psum, res, out, B, L2);
}